// Round 5
// baseline (103.481 us; speedup 1.0000x reference)
//
#include <hip/hip_runtime.h>
#include <math.h>

// Third-order scattering via double-Parseval:
//   out[b,i,j] = (1/MN^2) * sum_n xa_{b,i}[n] * d_{b,j}[n]
// xa_i = abs_eps(inv2(F_i * X)/MN), d_j = Re(inv2_un(F_j^2 * X)), X = fft2(x).
// X in NATURAL frequency layout. Inverse FFTs are conjugate-DIF: natural freq
// input -> permuted spatial output. All k_fields outputs share one fixed
// permutation (sigma_v x sigma_u), so the spatial dot products are unaffected.
//
// Hard-won constraints:
//  - R7: cooperative single-kernel fusion regressed 2.8x. Do not fuse.
//  - R8/R9: inverse FFT MUST be conjugate-DIF (largest span FIRST,
//    forward-butterfly form, conjugated twiddles).
//  - R10: XCD-affine k_dot remap regressed; float4 alone (R12) is good.
//  - R11 FAILED: branchless fma-butterfly regressed. KEEP divergent if/else
//    butterflies -- compiler if-conversion is optimal.
//  - R12 WIN: k_dot float4. R13 WIN: Hermitian d-pairing + 2-block P2 split.
//  - R14 WIN: k_dot j-split (acc[17]) + k_prep x4 split. 103.3us.
//    Model: small-grid kernels are per-block SERIAL-CHAIN bound; wall ~
//    per-block FFT-call count, blocks must stay <= 256.
//  - R15 (this round): k_fields "Config B" FFT: 2 rows per wave (rows on
//    lane halves), 4 complex pts/lane. Spans 64,32 in-register; 5 shfl
//    stages (h<=16, partners stay in 32-lane groups). P1 8->4 calls,
//    P2 4->2: chain 12->6. k_prep keeps old path (X natural). Also
//    k_prep G-blocks 33->132 (4 iters each).
//
// 3 dispatches:
//  k_prep   : blocks 0-7: (b,quarter) X=fft2(x); 8: zero out; 9-140: G_j/4.
//  k_fields : 196 blocks: 68 d-pair-half + 128 xa-half (Config B FFT).
//  k_dot    : 512 blocks = (b,i) x 4 k-slices x 2 j-halves.

#define PI_F 3.14159265358979323846f

// ---------- old 1-row path (k_prep only) ----------
__device__ __forceinline__ void make_tw(int lane, float* twr, float* twi) {
#pragma unroll
  for (int s = 0; s < 6; ++s) {
    int h = 32 >> s;
    float ang = -PI_F * (float)(lane & (h - 1)) / (float)h;
    float sv, cv;
    __sincosf(ang, &sv, &cv);
    twr[s] = cv; twi[s] = sv;
  }
  float ang = -PI_F * (float)lane / 64.0f;
  float sv, cv;
  __sincosf(ang, &sv, &cv);
  twr[6] = cv; twi[6] = sv;
}

// DIF radix-2, 1 row/wave, 2 pts/lane. Natural in; slot s holds X[brev7(s)].
template <int S>
__device__ __forceinline__ void fft128_dif(float& ar, float& ai, float& br, float& bi,
                                           const float* twr, const float* twi, int lane) {
  float s6r = twr[6], s6i = (S > 0) ? twi[6] : -twi[6];
  float ur = ar + br, ui = ai + bi;
  float vr = ar - br, vi = ai - bi;
  ar = ur; ai = ui;
  br = vr * s6r - vi * s6i;
  bi = vr * s6i + vi * s6r;
#pragma unroll
  for (int s = 0; s < 6; ++s) {
    int h = 32 >> s;
    float wr = twr[s], wi = (S > 0) ? twi[s] : -twi[s];
    bool hi = (lane & h) != 0;
    float pr, pi2;
    pr = __shfl_xor(ar, h, 64); pi2 = __shfl_xor(ai, h, 64);
    if (!hi) { ar += pr; ai += pi2; }
    else { float dr = pr - ar, di = pi2 - ai; ar = dr * wr - di * wi; ai = dr * wi + di * wr; }
    pr = __shfl_xor(br, h, 64); pi2 = __shfl_xor(bi, h, 64);
    if (!hi) { br += pr; bi += pi2; }
    else { float dr = pr - br, di = pi2 - bi; br = dr * wr - di * wi; bi = dr * wi + di * wr; }
  }
}

template <int NC>
__device__ __forceinline__ void transpose_r2c_n(float (&dr)[16], float (&di)[16],
    float (&er)[NC], float (&ei)[NC], float (&fr)[NC], float (&fi2)[NC],
    float2 (*tile)[128], int lane, int w, int colbase) {
#pragma unroll
  for (int ch = 0; ch < 2; ++ch) {
    if ((w >> 3) == ch) {
#pragma unroll
      for (int t = 0; t < 8; ++t) {
        int r = w * 8 + t;
        int rr = r & 63, sw = r & 15;
        tile[rr][lane ^ sw] = make_float2(dr[2 * t], di[2 * t]);
        tile[rr][(lane + 64) ^ sw] = make_float2(dr[2 * t + 1], di[2 * t + 1]);
      }
    }
    __syncthreads();
    {
      int sw = lane & 15;
#pragma unroll
      for (int ci = 0; ci < NC; ++ci) {
        int c = colbase + w * NC + ci;
        float2 v = tile[lane][c ^ sw];
        if (ch == 0) { er[ci] = v.x; ei[ci] = v.y; }
        else { fr[ci] = v.x; fi2[ci] = v.y; }
      }
    }
    __syncthreads();
  }
}

// ---------- new 2-row path (k_fields) ----------
// Lane layout: g = lane>>5 selects row/col, q = lane&31. Lane holds 4 complex
// values c[m] = positions q+32m of its row. DIF: span 64 (c0,c2)/(c1,c3) with
// W128^q / W128^(q+32); span 32 (c0,c1)/(c2,c3) with W64^q; then 5 shfl
// stages h=16..1 within 32-lane groups. Slot 32m+q holds X[brev7(32m+q)].
__device__ __forceinline__ void make_tw2(int q, float* t2r, float* t2i, float* hw) {
#pragma unroll
  for (int s = 0; s < 5; ++s) {
    int h = 16 >> s;
    float ang = -PI_F * (float)(q & (h - 1)) / (float)h;
    float sv, cv;
    __sincosf(ang, &sv, &cv);
    t2r[s] = cv; t2i[s] = sv;
  }
  float sv, cv;
  __sincosf(-PI_F * (float)q / 64.0f, &sv, &cv);         hw[0] = cv; hw[1] = sv;
  __sincosf(-PI_F * (float)(q + 32) / 64.0f, &sv, &cv);  hw[2] = cv; hw[3] = sv;
  __sincosf(-PI_F * (float)q / 32.0f, &sv, &cv);         hw[4] = cv; hw[5] = sv;
}

template <int S>
__device__ __forceinline__ void fft128x2_dif(float (&cr)[4], float (&ci)[4],
    const float* t2r, const float* t2i, const float* hw, int q) {
  float T0r = hw[0], T0i = (S > 0) ? hw[1] : -hw[1];
  float T1r = hw[2], T1i = (S > 0) ? hw[3] : -hw[3];
  float T2r = hw[4], T2i = (S > 0) ? hw[5] : -hw[5];
  // span 64: pairs (q, q+64) -> (c0,c2) tw W128^q; (q+32,q+96) -> (c1,c3) tw W128^(q+32)
  {
    float ur = cr[0] + cr[2], ui = ci[0] + ci[2];
    float vr = cr[0] - cr[2], vi = ci[0] - ci[2];
    cr[0] = ur; ci[0] = ui;
    cr[2] = vr * T0r - vi * T0i; ci[2] = vr * T0i + vi * T0r;
    ur = cr[1] + cr[3]; ui = ci[1] + ci[3];
    vr = cr[1] - cr[3]; vi = ci[1] - ci[3];
    cr[1] = ur; ci[1] = ui;
    cr[3] = vr * T1r - vi * T1i; ci[3] = vr * T1i + vi * T1r;
  }
  // span 32: (c0,c1) and (c2,c3), tw W64^q
  {
    float ur = cr[0] + cr[1], ui = ci[0] + ci[1];
    float vr = cr[0] - cr[1], vi = ci[0] - ci[1];
    cr[0] = ur; ci[0] = ui;
    cr[1] = vr * T2r - vi * T2i; ci[1] = vr * T2i + vi * T2r;
    ur = cr[2] + cr[3]; ui = ci[2] + ci[3];
    vr = cr[2] - cr[3]; vi = ci[2] - ci[3];
    cr[2] = ur; ci[2] = ui;
    cr[3] = vr * T2r - vi * T2i; ci[3] = vr * T2i + vi * T2r;
  }
  // 5 shfl stages within 32-lane groups (h<=16 keeps partners in-group)
#pragma unroll
  for (int s = 0; s < 5; ++s) {
    int h = 16 >> s;
    float wr = t2r[s], wi = (S > 0) ? t2i[s] : -t2i[s];
    bool hi = (q & h) != 0;
#pragma unroll
    for (int m = 0; m < 4; ++m) {
      float pr = __shfl_xor(cr[m], h, 64);
      float pi2 = __shfl_xor(ci[m], h, 64);
      if (!hi) { cr[m] += pr; ci[m] += pi2; }
      else { float dr = pr - cr[m], di = pi2 - ci[m];
             cr[m] = dr * wr - di * wi; ci[m] = dr * wi + di * wr; }
    }
  }
}

// blocks 0..7: (b,quarter): X[b] = fft2(x[b]) NATURAL (u,v) layout, P2 1/4.
// block 8: zero out[1344].
// blocks 9..140: G_j quarter: G_j(k) = 0.5*(F_j(k)^2 + F_j(-k)^2)
__global__ __launch_bounds__(1024, 2) void k_prep(const float* __restrict__ x,
    float2* __restrict__ X, float* __restrict__ out, const float* __restrict__ F,
    float* __restrict__ G) {
  __shared__ float2 tile[64][128];
  int tid = threadIdx.x;
  int bx = blockIdx.x;
  if (bx == 8) {
    if (tid < 1344) out[tid] = 0.f;
    return;
  }
  if (bx >= 9) {
    int q = bx - 9;
    int j = q >> 2, part = q & 3;
    const float* Fj = F + j * 16384;
    float* Gj = G + j * 16384;
#pragma unroll
    for (int it = 0; it < 4; ++it) {
      int k = part * 4096 + it * 1024 + tid;
      int u = k >> 7, v = k & 127;
      int un = (128 - u) & 127, vn = (128 - v) & 127;
      float f = Fj[k], fn = Fj[un * 128 + vn];
      Gj[k] = 0.5f * (f * f + fn * fn);
    }
    return;
  }
  int b = bx >> 2, quarter = bx & 3;
  int lane = tid & 63, w = tid >> 6;
  float twr[7], twi[7]; make_tw(lane, twr, twi);
  const float* xb = x + b * 16384;
  float dr[16], di[16];
  float er[2], ei[2], fr[2], fi2[2];
#pragma unroll
  for (int t = 0; t < 8; ++t) {  // P1 (duplicated across quarters): fwd v-FFT
    int r = w * 8 + t;
    float ar = xb[r * 128 + lane], ai2 = 0.f, br = xb[r * 128 + lane + 64], bi = 0.f;
    fft128_dif<1>(ar, ai2, br, bi, twr, twi, lane);
    dr[2 * t] = ar; di[2 * t] = ai2; dr[2 * t + 1] = br; di[2 * t + 1] = bi;
  }
  transpose_r2c_n<2>(dr, di, er, ei, fr, fi2, tile, lane, w, quarter * 32);
  int u0 = __brev((unsigned)lane) >> 25;  // brev7(lane); brev7(lane+64)=u0+1
#pragma unroll
  for (int ci = 0; ci < 2; ++ci) {  // P2 quarter: fwd u-FFT, brev scatter
    int c = quarter * 32 + w * 2 + ci;
    float ar = er[ci], ai2 = ei[ci], br = fr[ci], bi = fi2[ci];
    fft128_dif<1>(ar, ai2, br, bi, twr, twi, lane);
    int vn = __brev((unsigned)c) >> 25;
    X[b * 16384 + u0 * 128 + vn] = make_float2(ar, ai2);
    X[b * 16384 + (u0 + 1) * 128 + vn] = make_float2(br, bi);
  }
}

// blocks 0..67:  d-pairs: (b x 17 pairs) x 2 halves.
//   pair p: j0=2p, j1=2p+1 (p<16); p==16 singleton j0=32.
//   Y = (G_j0 + i G_j1) * X; inv2_un(Y) = d_j0 + i d_j1.
// blocks 68..195: xa: (b*32+i) x 2 halves: xa = abs_eps(inv2_un(F_i X)/MN).
// Config B FFT throughout: P1 4 calls (2 rows each), P2 2 calls (2 cols each).
__global__ __launch_bounds__(1024, 1) void k_fields(const float2* __restrict__ X,
    const float* __restrict__ F, const float* __restrict__ G,
    float* __restrict__ dfld, float* __restrict__ xa) {
  __shared__ float2 tile[64][128];
  int tid = threadIdx.x, lane = tid & 63, w = tid >> 6;
  int g = lane >> 5, q = lane & 31;
  int bx = blockIdx.x;
  bool isd = (bx < 68);
  int b, half;
  bool has1 = false;
  const float* g0 = nullptr; const float* g1 = nullptr; const float* Fb = nullptr;
  float* o0; float* o1 = nullptr;
  if (isd) {
    int dp = bx >> 1; half = bx & 1;
    b = dp / 17; int p = dp - b * 17;
    int j0 = 2 * p; has1 = (p < 16);
    g0 = G + j0 * 16384;
    g1 = G + (j0 + 1) * 16384;
    o0 = dfld + (b * 33 + j0) * 16384;
    o1 = dfld + (b * 33 + j0 + 1) * 16384;
  } else {
    int qq = bx - 68; int qi = qq >> 1; half = qq & 1;
    b = qi >> 5; int f = qi & 31;
    Fb = F + f * 16384;
    o0 = xa + qi * 16384;
  }
  float t2r[5], t2i[5], hw[6];
  make_tw2(q, t2r, t2i, hw);
  const float2* Xb = X + b * 16384;

  // P1: 4 calls; call k does rows r0=w*8+2k (g=0) and r0+1 (g=1).
  float sr[4][4], si[4][4];
#pragma unroll
  for (int k = 0; k < 4; ++k) {
    int r = w * 8 + 2 * k + g;
    float cr[4], ci[4];
#pragma unroll
    for (int m = 0; m < 4; ++m) {
      int p = q + 32 * m;
      float2 xv = Xb[r * 128 + p];
      if (isd) {
        float ga = g0[r * 128 + p];
        float gb = has1 ? g1[r * 128 + p] : 0.f;
        cr[m] = xv.x * ga - xv.y * gb; ci[m] = xv.y * ga + xv.x * gb;
      } else {
        float f0 = Fb[r * 128 + p];
        cr[m] = xv.x * f0; ci[m] = xv.y * f0;
      }
    }
    fft128x2_dif<-1>(cr, ci, t2r, t2i, hw, q);
#pragma unroll
    for (int m = 0; m < 4; ++m) { sr[k][m] = cr[m]; si[k][m] = ci[m]; }
  }

  // Transpose: write slots (32m+q) of row r; read u-positions (32mm+q) of
  // cols c = colbase + w*4 + 2j + g. Swizzle sw = row&15 both sides
  // ((q+32)&15 == q&15 keeps read sw uniform).
  float pr[2][4], pi2a[2][4];
  int colbase = half * 64;
#pragma unroll
  for (int ch = 0; ch < 2; ++ch) {
    if ((w >> 3) == ch) {
#pragma unroll
      for (int k = 0; k < 4; ++k) {
        int r = w * 8 + 2 * k + g;
        int rr = r & 63, sw = r & 15;
#pragma unroll
        for (int m = 0; m < 4; ++m)
          tile[rr][(32 * m + q) ^ sw] = make_float2(sr[k][m], si[k][m]);
      }
    }
    __syncthreads();
    {
      int sw = q & 15;
#pragma unroll
      for (int j = 0; j < 2; ++j) {
        int c = colbase + w * 4 + 2 * j + g;
#pragma unroll
        for (int mm = 0; mm < 2; ++mm) {
          float2 v = tile[32 * mm + q][c ^ sw];
          pr[j][2 * ch + mm] = v.x; pi2a[j][2 * ch + mm] = v.y;
        }
      }
    }
    __syncthreads();
  }

  // P2: 2 calls; call j does cols c0=colbase+w*4+2j (g=0) and c0+1 (g=1).
  const float sc = 1.0f / 16384.0f;
#pragma unroll
  for (int j = 0; j < 2; ++j) {
    fft128x2_dif<-1>(pr[j], pi2a[j], t2r, t2i, hw, q);
    int c = colbase + w * 4 + 2 * j + g;
#pragma unroll
    for (int m = 0; m < 4; ++m) {
      int su = 32 * m + q;
      if (isd) {
        o0[c * 128 + su] = pr[j][m];
        if (has1) o1[c * 128 + su] = pi2a[j][m];
      } else {
        float tr = pr[j][m] * sc, ti = pi2a[j][m] * sc;
        o0[c * 128 + su] = sqrtf(tr * tr + ti * ti + 1e-6f);
      }
    }
  }
}

// [R14] 512 blocks = (b,i)[64] x slice[4] x jhalf[2]; 512 threads; acc[17].
__global__ __launch_bounds__(512) void k_dot(const float* __restrict__ xa,
    const float* __restrict__ dfld, float* __restrict__ out) {
  int qb = blockIdx.x;
  int im = qb >> 3;                // 0..63  (b*32+i)
  int slice = (qb >> 1) & 3;       // 0..3
  int jh = qb & 1;                 // 0..1
  int b = im >> 5, i = im & 31;
  int j0 = jh * 17;                // 0 or 17
  int t = threadIdx.x;             // 0..511
  const float4* xr = (const float4*)(xa + im * 16384 + slice * 4096);
  const float4* db = (const float4*)(dfld + (b * 33 + j0) * 16384 + slice * 4096);
  // jh=1,b=1: j index 16 reads one field past dfld (inside ws, xa region);
  // loads safe, result discarded at emit.
  float acc[17];
#pragma unroll
  for (int j = 0; j < 17; ++j) acc[j] = 0.f;
#pragma unroll
  for (int it = 0; it < 2; ++it) {
    int k = it * 512 + t;          // float4 index, 1024 per slice
    float4 xv = xr[k];
#pragma unroll
    for (int j = 0; j < 17; ++j) {
      float4 dv = db[j * 4096 + k];
      acc[j] += xv.x * dv.x + xv.y * dv.y + xv.z * dv.z + xv.w * dv.w;
    }
  }
#pragma unroll
  for (int j = 0; j < 17; ++j) {
#pragma unroll
    for (int off = 32; off > 0; off >>= 1) acc[j] += __shfl_xor(acc[j], off, 64);
  }
  __shared__ float red[8][17];
  int w = t >> 6, lane = t & 63;
  if (lane == 0) {
#pragma unroll
    for (int j = 0; j < 17; ++j) red[w][j] = acc[j];
  }
  __syncthreads();
  if (t < 17) {
    int j = j0 + t;                // global j 0..33
    float s = 0.f;
#pragma unroll
    for (int w2 = 0; w2 < 8; ++w2) s += red[w2][t];
    int j1 = i >> 3, l1 = i & 7;
    const int pref[4] = {0, 264, 464, 600};
    int per = (4 - j1) * 8 + 1;
    int start = pref[j1] + l1 * per;
    int pos = -1;
    if (j == 32) pos = start + per - 1;
    else if (j < 32) {
      int j2 = j >> 3;
      if (j2 >= j1) pos = start + (j2 - j1) * 8 + (j & 7);
    }
    if (pos >= 0)
      atomicAdd(out + b * 672 + pos, s * (1.0f / 16384.0f) * (1.0f / 16384.0f));
  }
}

extern "C" void kernel_launch(void* const* d_in, const int* in_sizes, int n_in,
                              void* d_out, int out_size, void* d_ws, size_t ws_size,
                              hipStream_t stream) {
  (void)in_sizes; (void)n_in; (void)out_size; (void)ws_size;
  const float* x = (const float*)d_in[0];   // (2,1,128,128)
  const float* F = (const float*)d_in[1];   // (1,33,128,128)
  float* out = (float*)d_out;               // (2,672)
  char* ws = (char*)d_ws;
  // ws: X @0 (262144 B) | dfld @262144 (4325376 B) | xa @4587520 (4194304 B)
  //     | G @8781824 (2162688 B)
  float2* X = (float2*)(ws + 0);
  float* dfld = (float*)(ws + 262144);
  float* xa = (float*)(ws + 4587520);
  float* G = (float*)(ws + 8781824);

  hipLaunchKernelGGL(k_prep, dim3(141), dim3(1024), 0, stream, x, X, out, F, G);
  hipLaunchKernelGGL(k_fields, dim3(196), dim3(1024), 0, stream, X, F, G, dfld, xa);
  hipLaunchKernelGGL(k_dot, dim3(512), dim3(512), 0, stream, xa, dfld, out);
}

// Round 6
// 96.735 us; speedup vs baseline: 1.0697x; 1.0697x over previous
//
#include <hip/hip_runtime.h>
#include <math.h>

// Third-order scattering via double-Parseval:
//   out[b,i,j] = (1/MN^2) * sum_n xa_{b,i}[n] * d_{b,j}[n]
// xa_i = abs_eps(inv2(F_i * X)/MN), d_j = Re(inv2_un(F_j^2 * X)), X = fft2(x).
// X in NATURAL frequency layout. Inverse FFTs are conjugate-DIF: natural freq
// input -> permuted spatial output. All k_fields outputs share one fixed
// permutation, so the spatial dot products are unaffected.
//
// Hard-won constraints / model:
//  - R7: cooperative single-kernel fusion regressed 2.8x. Do not fuse.
//  - R8/R9: inverse FFT MUST be conjugate-DIF (largest span FIRST,
//    forward-butterfly form, conjugated twiddles).
//  - R10: XCD-affine k_dot remap regressed; float4 alone (R12) is good.
//  - R11 FAILED: branchless fma-butterfly regressed. KEEP divergent if/else
//    butterflies (exception: stages whose twiddle is EXACTLY 1 -- R16).
//  - R12 WIN: k_dot float4. R13 WIN: Hermitian d-pairing + 2-block P2 split.
//  - R14 WIN: k_dot j-split + k_prep x4 split. 103.3us.
//  - R15 NEUTRAL: Config B (2 rows/wave) cut DS ops 29%, VALU 0% -> no
//    change. MODEL: FFT kernels are VALU-ISSUE bound (~8 VALU/point-stage,
//    DS hidden); wall ~ waves/SIMD x VALU x 2cyc. Budget: fills 86us +
//    k_fields ~5.5 + k_prep ~4.5 + k_dot ~2 + gaps ~4.
//  - R16 (this round): (a) k_prep P1 real-row pairing: 2 real rows per
//    complex FFT + shfl unpack (P1 8->4 calls, -25% k_prep VALU);
//    (b) hardcoded twiddle-free h=1 stage (bit-identical, -6% both FFTs);
//    (c) k_dot j-quarter split: 1024 blocks, acc[9], tree 54 DS.
//
// 3 dispatches:
//  k_prep   : blocks 0-7: (b,quarter) X=fft2(x) w/ real-pair P1; 8: zero out;
//             9-140: G_j quarters.
//  k_fields : 196 blocks: 68 d-pair-half + 128 xa-half (Config B FFT).
//  k_dot    : 1024 blocks = (b,i) x 4 k-slices x 4 j-quarters.

#define PI_F 3.14159265358979323846f

// ---------- old 1-row path (k_prep only) ----------
__device__ __forceinline__ void make_tw(int lane, float* twr, float* twi) {
#pragma unroll
  for (int s = 0; s < 6; ++s) {
    int h = 32 >> s;
    float ang = -PI_F * (float)(lane & (h - 1)) / (float)h;
    float sv, cv;
    __sincosf(ang, &sv, &cv);
    twr[s] = cv; twi[s] = sv;
  }
  float ang = -PI_F * (float)lane / 64.0f;
  float sv, cv;
  __sincosf(ang, &sv, &cv);
  twr[6] = cv; twi[6] = sv;
}

// DIF radix-2, 1 row/wave, 2 pts/lane. Natural in; slot s holds X[brev7(s)].
// Last stage (h=1) has twiddle == 1 exactly: hardcoded add/sub (R16).
template <int S>
__device__ __forceinline__ void fft128_dif(float& ar, float& ai, float& br, float& bi,
                                           const float* twr, const float* twi, int lane) {
  float s6r = twr[6], s6i = (S > 0) ? twi[6] : -twi[6];
  float ur = ar + br, ui = ai + bi;
  float vr = ar - br, vi = ai - bi;
  ar = ur; ai = ui;
  br = vr * s6r - vi * s6i;
  bi = vr * s6i + vi * s6r;
#pragma unroll
  for (int s = 0; s < 5; ++s) {  // h = 32,16,8,4,2
    int h = 32 >> s;
    float wr = twr[s], wi = (S > 0) ? twi[s] : -twi[s];
    bool hi = (lane & h) != 0;
    float pr, pi2;
    pr = __shfl_xor(ar, h, 64); pi2 = __shfl_xor(ai, h, 64);
    if (!hi) { ar += pr; ai += pi2; }
    else { float dr = pr - ar, di = pi2 - ai; ar = dr * wr - di * wi; ai = dr * wi + di * wr; }
    pr = __shfl_xor(br, h, 64); pi2 = __shfl_xor(bi, h, 64);
    if (!hi) { br += pr; bi += pi2; }
    else { float dr = pr - br, di = pi2 - bi; br = dr * wr - di * wi; bi = dr * wi + di * wr; }
  }
  {  // h = 1: twiddle exactly 1 -> pure add/sub
    bool hi = (lane & 1) != 0;
    float pr, pi2;
    pr = __shfl_xor(ar, 1, 64); pi2 = __shfl_xor(ai, 1, 64);
    if (!hi) { ar += pr; ai += pi2; } else { ar = pr - ar; ai = pi2 - ai; }
    pr = __shfl_xor(br, 1, 64); pi2 = __shfl_xor(bi, 1, 64);
    if (!hi) { br += pr; bi += pi2; } else { br = pr - br; bi = pi2 - bi; }
  }
}

template <int NC>
__device__ __forceinline__ void transpose_r2c_n(float (&dr)[16], float (&di)[16],
    float (&er)[NC], float (&ei)[NC], float (&fr)[NC], float (&fi2)[NC],
    float2 (*tile)[128], int lane, int w, int colbase) {
#pragma unroll
  for (int ch = 0; ch < 2; ++ch) {
    if ((w >> 3) == ch) {
#pragma unroll
      for (int t = 0; t < 8; ++t) {
        int r = w * 8 + t;
        int rr = r & 63, sw = r & 15;
        tile[rr][lane ^ sw] = make_float2(dr[2 * t], di[2 * t]);
        tile[rr][(lane + 64) ^ sw] = make_float2(dr[2 * t + 1], di[2 * t + 1]);
      }
    }
    __syncthreads();
    {
      int sw = lane & 15;
#pragma unroll
      for (int ci = 0; ci < NC; ++ci) {
        int c = colbase + w * NC + ci;
        float2 v = tile[lane][c ^ sw];
        if (ch == 0) { er[ci] = v.x; ei[ci] = v.y; }
        else { fr[ci] = v.x; fi2[ci] = v.y; }
      }
    }
    __syncthreads();
  }
}

// ---------- 2-row path (k_fields) ----------
// Lane layout: g = lane>>5 selects row/col, q = lane&31. Lane holds 4 complex
// values c[m] = positions q+32m of its row. Spans 64,32 in-register; 4 shfl
// stages h=16..2; h=1 hardcoded twiddle-free. Slot 32m+q -> X[brev7(32m+q)].
__device__ __forceinline__ void make_tw2(int q, float* t2r, float* t2i, float* hw) {
#pragma unroll
  for (int s = 0; s < 5; ++s) {
    int h = 16 >> s;
    float ang = -PI_F * (float)(q & (h - 1)) / (float)h;
    float sv, cv;
    __sincosf(ang, &sv, &cv);
    t2r[s] = cv; t2i[s] = sv;
  }
  float sv, cv;
  __sincosf(-PI_F * (float)q / 64.0f, &sv, &cv);         hw[0] = cv; hw[1] = sv;
  __sincosf(-PI_F * (float)(q + 32) / 64.0f, &sv, &cv);  hw[2] = cv; hw[3] = sv;
  __sincosf(-PI_F * (float)q / 32.0f, &sv, &cv);         hw[4] = cv; hw[5] = sv;
}

template <int S>
__device__ __forceinline__ void fft128x2_dif(float (&cr)[4], float (&ci)[4],
    const float* t2r, const float* t2i, const float* hw, int q) {
  float T0r = hw[0], T0i = (S > 0) ? hw[1] : -hw[1];
  float T1r = hw[2], T1i = (S > 0) ? hw[3] : -hw[3];
  float T2r = hw[4], T2i = (S > 0) ? hw[5] : -hw[5];
  // span 64: (c0,c2) tw W128^q; (c1,c3) tw W128^(q+32)
  {
    float ur = cr[0] + cr[2], ui = ci[0] + ci[2];
    float vr = cr[0] - cr[2], vi = ci[0] - ci[2];
    cr[0] = ur; ci[0] = ui;
    cr[2] = vr * T0r - vi * T0i; ci[2] = vr * T0i + vi * T0r;
    ur = cr[1] + cr[3]; ui = ci[1] + ci[3];
    vr = cr[1] - cr[3]; vi = ci[1] - ci[3];
    cr[1] = ur; ci[1] = ui;
    cr[3] = vr * T1r - vi * T1i; ci[3] = vr * T1i + vi * T1r;
  }
  // span 32: (c0,c1),(c2,c3) tw W64^q
  {
    float ur = cr[0] + cr[1], ui = ci[0] + ci[1];
    float vr = cr[0] - cr[1], vi = ci[0] - ci[1];
    cr[0] = ur; ci[0] = ui;
    cr[1] = vr * T2r - vi * T2i; ci[1] = vr * T2i + vi * T2r;
    ur = cr[2] + cr[3]; ui = ci[2] + ci[3];
    vr = cr[2] - cr[3]; vi = ci[2] - ci[3];
    cr[2] = ur; ci[2] = ui;
    cr[3] = vr * T2r - vi * T2i; ci[3] = vr * T2i + vi * T2r;
  }
  // 4 shfl stages h=16..2
#pragma unroll
  for (int s = 0; s < 4; ++s) {
    int h = 16 >> s;
    float wr = t2r[s], wi = (S > 0) ? t2i[s] : -t2i[s];
    bool hi = (q & h) != 0;
#pragma unroll
    for (int m = 0; m < 4; ++m) {
      float pr = __shfl_xor(cr[m], h, 64);
      float pi2 = __shfl_xor(ci[m], h, 64);
      if (!hi) { cr[m] += pr; ci[m] += pi2; }
      else { float dr = pr - cr[m], di = pi2 - ci[m];
             cr[m] = dr * wr - di * wi; ci[m] = dr * wi + di * wr; }
    }
  }
  {  // h = 1: twiddle exactly 1
    bool hi = (q & 1) != 0;
#pragma unroll
    for (int m = 0; m < 4; ++m) {
      float pr = __shfl_xor(cr[m], 1, 64);
      float pi2 = __shfl_xor(ci[m], 1, 64);
      if (!hi) { cr[m] += pr; ci[m] += pi2; }
      else { cr[m] = pr - cr[m]; ci[m] = pi2 - ci[m]; }
    }
  }
}

// blocks 0..7: (b,quarter): X[b] = fft2(x[b]) NATURAL (u,v) layout.
//   P1 [R16]: real-row pairing -- rows (2t,2t+1) as one complex FFT + unpack
//   via conj(Z(-v)) fetched with lane-constant bpermute indices.
// block 8: zero out[1344].
// blocks 9..140: G_j quarter: G_j(k) = 0.5*(F_j(k)^2 + F_j(-k)^2)
__global__ __launch_bounds__(1024, 2) void k_prep(const float* __restrict__ x,
    float2* __restrict__ X, float* __restrict__ out, const float* __restrict__ F,
    float* __restrict__ G) {
  __shared__ float2 tile[64][128];
  int tid = threadIdx.x;
  int bx = blockIdx.x;
  if (bx == 8) {
    if (tid < 1344) out[tid] = 0.f;
    return;
  }
  if (bx >= 9) {
    int q = bx - 9;
    int j = q >> 2, part = q & 3;
    const float* Fj = F + j * 16384;
    float* Gj = G + j * 16384;
#pragma unroll
    for (int it = 0; it < 4; ++it) {
      int k = part * 4096 + it * 1024 + tid;
      int u = k >> 7, v = k & 127;
      int un = (128 - u) & 127, vn = (128 - v) & 127;
      float f = Fj[k], fn = Fj[un * 128 + vn];
      Gj[k] = 0.5f * (f * f + fn * fn);
    }
    return;
  }
  int b = bx >> 2, quarter = bx & 3;
  int lane = tid & 63, w = tid >> 6;
  float twr[7], twi[7]; make_tw(lane, twr, twi);
  const float* xb = x + b * 16384;
  // lane-constant unpack slot indices:
  // a-slot freq v=u0 -> -v at slot brev7((128-u0)&127); b-slot v=u0+1.
  int u0 = __brev((unsigned)lane) >> 25;
  int spA = __brev((unsigned)((128 - u0) & 127)) >> 25;
  int spB = __brev((unsigned)(127 - u0)) >> 25;
  float dr[16], di[16];
  float er[2], ei[2], fr[2], fi2[2];
#pragma unroll
  for (int t = 0; t < 4; ++t) {  // P1: rows (2t, 2t+1) of this wave, paired
    int r0 = w * 8 + 2 * t;
    float ar = xb[r0 * 128 + lane],      ai2 = xb[(r0 + 1) * 128 + lane];
    float br = xb[r0 * 128 + lane + 64], bi  = xb[(r0 + 1) * 128 + lane + 64];
    fft128_dif<1>(ar, ai2, br, bi, twr, twi, lane);
    // unpack a-slot: fetch Z at slot spA (a-regs if <64 else b-regs)
    int la = spA & 63;
    float fAr = __shfl(ar, la, 64), fAi = __shfl(ai2, la, 64);
    float fBr = __shfl(br, la, 64), fBi = __shfl(bi, la, 64);
    float Pr = (spA < 64) ? fAr : fBr, Pi = (spA < 64) ? fAi : fBi;
    float X0r = 0.5f * (ar + Pr),  X0i = 0.5f * (ai2 - Pi);
    float X1r = 0.5f * (ai2 + Pi), X1i = 0.5f * (Pr - ar);
    // unpack b-slot
    int lb = spB & 63;
    float gAr = __shfl(ar, lb, 64), gAi = __shfl(ai2, lb, 64);
    float gBr = __shfl(br, lb, 64), gBi = __shfl(bi, lb, 64);
    float Qr = (spB < 64) ? gAr : gBr, Qi = (spB < 64) ? gAi : gBi;
    float Y0r = 0.5f * (br + Qr), Y0i = 0.5f * (bi - Qi);
    float Y1r = 0.5f * (bi + Qi), Y1i = 0.5f * (Qr - br);
    // row 2t (even): spectrum X0/Y0; row 2t+1: X1/Y1
    dr[2 * (2 * t)] = X0r;     di[2 * (2 * t)] = X0i;
    dr[2 * (2 * t) + 1] = Y0r; di[2 * (2 * t) + 1] = Y0i;
    dr[2 * (2 * t + 1)] = X1r;     di[2 * (2 * t + 1)] = X1i;
    dr[2 * (2 * t + 1) + 1] = Y1r; di[2 * (2 * t + 1) + 1] = Y1i;
  }
  transpose_r2c_n<2>(dr, di, er, ei, fr, fi2, tile, lane, w, quarter * 32);
#pragma unroll
  for (int ci = 0; ci < 2; ++ci) {  // P2 quarter: fwd u-FFT, brev scatter
    int c = quarter * 32 + w * 2 + ci;
    float ar = er[ci], ai2 = ei[ci], br = fr[ci], bi = fi2[ci];
    fft128_dif<1>(ar, ai2, br, bi, twr, twi, lane);
    int vn = __brev((unsigned)c) >> 25;
    X[b * 16384 + u0 * 128 + vn] = make_float2(ar, ai2);
    X[b * 16384 + (u0 + 1) * 128 + vn] = make_float2(br, bi);
  }
}

// blocks 0..67:  d-pairs: (b x 17 pairs) x 2 halves.
//   pair p: j0=2p, j1=2p+1 (p<16); p==16 singleton j0=32.
//   Y = (G_j0 + i G_j1) * X; inv2_un(Y) = d_j0 + i d_j1.
// blocks 68..195: xa: (b*32+i) x 2 halves: xa = abs_eps(inv2_un(F_i X)/MN).
__global__ __launch_bounds__(1024, 1) void k_fields(const float2* __restrict__ X,
    const float* __restrict__ F, const float* __restrict__ G,
    float* __restrict__ dfld, float* __restrict__ xa) {
  __shared__ float2 tile[64][128];
  int tid = threadIdx.x, lane = tid & 63, w = tid >> 6;
  int g = lane >> 5, q = lane & 31;
  int bx = blockIdx.x;
  bool isd = (bx < 68);
  int b, half;
  bool has1 = false;
  const float* g0 = nullptr; const float* g1 = nullptr; const float* Fb = nullptr;
  float* o0; float* o1 = nullptr;
  if (isd) {
    int dp = bx >> 1; half = bx & 1;
    b = dp / 17; int p = dp - b * 17;
    int j0 = 2 * p; has1 = (p < 16);
    g0 = G + j0 * 16384;
    g1 = G + (j0 + 1) * 16384;
    o0 = dfld + (b * 33 + j0) * 16384;
    o1 = dfld + (b * 33 + j0 + 1) * 16384;
  } else {
    int qq = bx - 68; int qi = qq >> 1; half = qq & 1;
    b = qi >> 5; int f = qi & 31;
    Fb = F + f * 16384;
    o0 = xa + qi * 16384;
  }
  float t2r[5], t2i[5], hw[6];
  make_tw2(q, t2r, t2i, hw);
  const float2* Xb = X + b * 16384;

  // P1: 4 calls; call k does rows r0=w*8+2k (g=0) and r0+1 (g=1).
  float sr[4][4], si[4][4];
#pragma unroll
  for (int k = 0; k < 4; ++k) {
    int r = w * 8 + 2 * k + g;
    float cr[4], ci[4];
#pragma unroll
    for (int m = 0; m < 4; ++m) {
      int p = q + 32 * m;
      float2 xv = Xb[r * 128 + p];
      if (isd) {
        float ga = g0[r * 128 + p];
        float gb = has1 ? g1[r * 128 + p] : 0.f;
        cr[m] = xv.x * ga - xv.y * gb; ci[m] = xv.y * ga + xv.x * gb;
      } else {
        float f0 = Fb[r * 128 + p];
        cr[m] = xv.x * f0; ci[m] = xv.y * f0;
      }
    }
    fft128x2_dif<-1>(cr, ci, t2r, t2i, hw, q);
#pragma unroll
    for (int m = 0; m < 4; ++m) { sr[k][m] = cr[m]; si[k][m] = ci[m]; }
  }

  // Transpose: write slots (32m+q) of row r; read u-positions (32mm+q) of
  // cols c = colbase + w*4 + 2j + g. sw = row&15 both sides.
  float pr[2][4], pi2a[2][4];
  int colbase = half * 64;
#pragma unroll
  for (int ch = 0; ch < 2; ++ch) {
    if ((w >> 3) == ch) {
#pragma unroll
      for (int k = 0; k < 4; ++k) {
        int r = w * 8 + 2 * k + g;
        int rr = r & 63, sw = r & 15;
#pragma unroll
        for (int m = 0; m < 4; ++m)
          tile[rr][(32 * m + q) ^ sw] = make_float2(sr[k][m], si[k][m]);
      }
    }
    __syncthreads();
    {
      int sw = q & 15;
#pragma unroll
      for (int j = 0; j < 2; ++j) {
        int c = colbase + w * 4 + 2 * j + g;
#pragma unroll
        for (int mm = 0; mm < 2; ++mm) {
          float2 v = tile[32 * mm + q][c ^ sw];
          pr[j][2 * ch + mm] = v.x; pi2a[j][2 * ch + mm] = v.y;
        }
      }
    }
    __syncthreads();
  }

  // P2: 2 calls; call j does cols c0=colbase+w*4+2j (g=0) and c0+1 (g=1).
  const float sc = 1.0f / 16384.0f;
#pragma unroll
  for (int j = 0; j < 2; ++j) {
    fft128x2_dif<-1>(pr[j], pi2a[j], t2r, t2i, hw, q);
    int c = colbase + w * 4 + 2 * j + g;
#pragma unroll
    for (int m = 0; m < 4; ++m) {
      int su = 32 * m + q;
      if (isd) {
        o0[c * 128 + su] = pr[j][m];
        if (has1) o1[c * 128 + su] = pi2a[j][m];
      } else {
        float tr = pr[j][m] * sc, ti = pi2a[j][m] * sc;
        o0[c * 128 + su] = sqrtf(tr * tr + ti * ti + 1e-6f);
      }
    }
  }
}

// [R16] 1024 blocks = (b,i)[64] x slice[4] x jquarter[4]; 512 threads;
// acc[9]; tree 54 DS; 4 blocks/CU (2048 thr). j = 9*jq + t covers 0..35;
// j>=34 reads spill into xa workspace region (safe) and are discarded at
// emit (j<33 guard), same proven pattern as R14.
__global__ __launch_bounds__(512) void k_dot(const float* __restrict__ xa,
    const float* __restrict__ dfld, float* __restrict__ out) {
  int qb = blockIdx.x;
  int im = qb >> 4;                // 0..63  (b*32+i)
  int slice = (qb >> 2) & 3;       // 0..3
  int jq = qb & 3;                 // 0..3
  int b = im >> 5, i = im & 31;
  int j0 = jq * 9;                 // 0,9,18,27
  int t = threadIdx.x;             // 0..511
  const float4* xr = (const float4*)(xa + im * 16384 + slice * 4096);
  const float4* db = (const float4*)(dfld + (b * 33 + j0) * 16384 + slice * 4096);
  float acc[9];
#pragma unroll
  for (int j = 0; j < 9; ++j) acc[j] = 0.f;
#pragma unroll
  for (int it = 0; it < 2; ++it) {
    int k = it * 512 + t;          // float4 index, 1024 per slice
    float4 xv = xr[k];
#pragma unroll
    for (int j = 0; j < 9; ++j) {
      float4 dv = db[j * 4096 + k];
      acc[j] += xv.x * dv.x + xv.y * dv.y + xv.z * dv.z + xv.w * dv.w;
    }
  }
#pragma unroll
  for (int j = 0; j < 9; ++j) {
#pragma unroll
    for (int off = 32; off > 0; off >>= 1) acc[j] += __shfl_xor(acc[j], off, 64);
  }
  __shared__ float red[8][9];
  int w = t >> 6, lane = t & 63;
  if (lane == 0) {
#pragma unroll
    for (int j = 0; j < 9; ++j) red[w][j] = acc[j];
  }
  __syncthreads();
  if (t < 9) {
    int j = j0 + t;                // global j 0..35
    float s = 0.f;
#pragma unroll
    for (int w2 = 0; w2 < 8; ++w2) s += red[w2][t];
    int j1 = i >> 3, l1 = i & 7;
    const int pref[4] = {0, 264, 464, 600};
    int per = (4 - j1) * 8 + 1;
    int start = pref[j1] + l1 * per;
    int pos = -1;
    if (j == 32) pos = start + per - 1;
    else if (j < 32) {
      int j2 = j >> 3;
      if (j2 >= j1) pos = start + (j2 - j1) * 8 + (j & 7);
    }
    if (pos >= 0)
      atomicAdd(out + b * 672 + pos, s * (1.0f / 16384.0f) * (1.0f / 16384.0f));
  }
}

extern "C" void kernel_launch(void* const* d_in, const int* in_sizes, int n_in,
                              void* d_out, int out_size, void* d_ws, size_t ws_size,
                              hipStream_t stream) {
  (void)in_sizes; (void)n_in; (void)out_size; (void)ws_size;
  const float* x = (const float*)d_in[0];   // (2,1,128,128)
  const float* F = (const float*)d_in[1];   // (1,33,128,128)
  float* out = (float*)d_out;               // (2,672)
  char* ws = (char*)d_ws;
  // ws: X @0 (262144 B) | dfld @262144 (4325376 B) | xa @4587520 (4194304 B)
  //     | G @8781824 (2162688 B)
  float2* X = (float2*)(ws + 0);
  float* dfld = (float*)(ws + 262144);
  float* xa = (float*)(ws + 4587520);
  float* G = (float*)(ws + 8781824);

  hipLaunchKernelGGL(k_prep, dim3(141), dim3(1024), 0, stream, x, X, out, F, G);
  hipLaunchKernelGGL(k_fields, dim3(196), dim3(1024), 0, stream, X, F, G, dfld, xa);
  hipLaunchKernelGGL(k_dot, dim3(1024), dim3(512), 0, stream, xa, dfld, out);
}

// Round 7
// 95.884 us; speedup vs baseline: 1.0792x; 1.0089x over previous
//
#include <hip/hip_runtime.h>
#include <math.h>

// Third-order scattering via double-Parseval:
//   out[b,i,j] = (1/MN^2) * sum_n xa_{b,i}[n] * d_{b,j}[n]
// xa_i = abs_eps(inv2(F_i * X)/MN), d_j = Re(inv2_un(F_j^2 * X)), X = fft2(x).
// X in NATURAL frequency layout. Inverse FFTs are conjugate-DIF: natural freq
// input -> permuted spatial output. All k_fields outputs share one fixed
// permutation, so the spatial dot products are unaffected.
//
// Hard-won constraints / model:
//  - R7: cooperative single-kernel fusion regressed 2.8x. Do not fuse.
//  - R8/R9: inverse FFT MUST be conjugate-DIF (largest span FIRST,
//    forward-butterfly form, conjugated twiddles).
//  - R10: XCD-affine k_dot remap regressed; float4 alone (R12) is good.
//  - R11 FAILED: branchless fma-butterfly regressed. KEEP divergent if/else
//    butterflies (exception: stages with twiddle EXACTLY 1 or +-i -- those
//    become add/sub/swap selects, bit-equivalent: R16 h=1, R17 h=2).
//  - R12 WIN: k_dot float4. R13 WIN: Hermitian d-pairing + 2-block P2 split.
//  - R14 WIN: k_dot j-split + k_prep x4 split. 103.3us.
//  - R15 NEUTRAL: Config B cut DS 29%, VALU 0% -> no change. MODEL: FFT
//    kernels are VALU-ISSUE bound (DS hidden); wall ~ per-block VALU.
//  - R16 WIN: k_prep P1 real-row pairing + trivial h=1 stage + k_dot
//    j-quarters. 96.7us. Budget: fills ~84.6 + kernels ~8 + gaps ~3.
//  - R17 (this round): exact VALU cuts only: (a) trivial h=2 stage
//    (tw in {1,-i}/{1,+i} -> swap/negate select); (b) radix-4 merge of
//    in-register spans in fft128x2 (T1 absorbed, T0*T2 precomputed as
//    W128^3q; 40->34 VALU/call); (c) k_prep FFT x8 split (P2 1 call).
//
// 3 dispatches:
//  k_prep   : blocks 0-15: (b,eighth) X=fft2(x) w/ real-pair P1; 16: zero;
//             17-148: G_j quarters.
//  k_fields : 196 blocks: 68 d-pair-half + 128 xa-half (Config B FFT).
//  k_dot    : 1024 blocks = (b,i) x 4 k-slices x 4 j-quarters.

#define PI_F 3.14159265358979323846f

// ---------- 1-row path (k_prep) ----------
// twr/twi[0..3]: stages h=32,16,8,4; [4]: span-64 head W128^lane.
__device__ __forceinline__ void make_tw(int lane, float* twr, float* twi) {
#pragma unroll
  for (int s = 0; s < 4; ++s) {
    int h = 32 >> s;
    float ang = -PI_F * (float)(lane & (h - 1)) / (float)h;
    float sv, cv;
    __sincosf(ang, &sv, &cv);
    twr[s] = cv; twi[s] = sv;
  }
  float ang = -PI_F * (float)lane / 64.0f;
  float sv, cv;
  __sincosf(ang, &sv, &cv);
  twr[4] = cv; twi[4] = sv;
}

// DIF radix-2, 1 row/wave, 2 pts/lane. Natural in; slot s holds X[brev7(s)].
// h=2 (tw in {1,-i}) and h=1 (tw=1) stages hardcoded -- bit-equivalent.
template <int S>
__device__ __forceinline__ void fft128_dif(float& ar, float& ai, float& br, float& bi,
                                           const float* twr, const float* twi, int lane) {
  float s6r = twr[4], s6i = (S > 0) ? twi[4] : -twi[4];
  float ur = ar + br, ui = ai + bi;
  float vr = ar - br, vi = ai - bi;
  ar = ur; ai = ui;
  br = vr * s6r - vi * s6i;
  bi = vr * s6i + vi * s6r;
#pragma unroll
  for (int s = 0; s < 4; ++s) {  // h = 32,16,8,4
    int h = 32 >> s;
    float wr = twr[s], wi = (S > 0) ? twi[s] : -twi[s];
    bool hi = (lane & h) != 0;
    float pr, pi2;
    pr = __shfl_xor(ar, h, 64); pi2 = __shfl_xor(ai, h, 64);
    if (!hi) { ar += pr; ai += pi2; }
    else { float dr = pr - ar, di = pi2 - ai; ar = dr * wr - di * wi; ai = dr * wi + di * wr; }
    pr = __shfl_xor(br, h, 64); pi2 = __shfl_xor(bi, h, 64);
    if (!hi) { br += pr; bi += pi2; }
    else { float dr = pr - br, di = pi2 - bi; br = dr * wr - di * wi; bi = dr * wi + di * wr; }
  }
  {  // h = 2: tw in {1, -i} fwd / {1, +i} inv -> swap/negate
    bool hi = (lane & 2) != 0, odd = (lane & 1) != 0;
    float pr, pi2;
    pr = __shfl_xor(ar, 2, 64); pi2 = __shfl_xor(ai, 2, 64);
    if (!hi) { ar += pr; ai += pi2; }
    else {
      float dr = pr - ar, di = pi2 - ai;
      if (!odd) { ar = dr; ai = di; }
      else if (S > 0) { ar = di; ai = -dr; }
      else { ar = -di; ai = dr; }
    }
    pr = __shfl_xor(br, 2, 64); pi2 = __shfl_xor(bi, 2, 64);
    if (!hi) { br += pr; bi += pi2; }
    else {
      float dr = pr - br, di = pi2 - bi;
      if (!odd) { br = dr; bi = di; }
      else if (S > 0) { br = di; bi = -dr; }
      else { br = -di; bi = dr; }
    }
  }
  {  // h = 1: tw = 1
    bool hi = (lane & 1) != 0;
    float pr, pi2;
    pr = __shfl_xor(ar, 1, 64); pi2 = __shfl_xor(ai, 1, 64);
    if (!hi) { ar += pr; ai += pi2; } else { ar = pr - ar; ai = pi2 - ai; }
    pr = __shfl_xor(br, 1, 64); pi2 = __shfl_xor(bi, 1, 64);
    if (!hi) { br += pr; bi += pi2; } else { br = pr - br; bi = pi2 - bi; }
  }
}

template <int NC>
__device__ __forceinline__ void transpose_r2c_n(float (&dr)[16], float (&di)[16],
    float (&er)[NC], float (&ei)[NC], float (&fr)[NC], float (&fi2)[NC],
    float2 (*tile)[128], int lane, int w, int colbase) {
#pragma unroll
  for (int ch = 0; ch < 2; ++ch) {
    if ((w >> 3) == ch) {
#pragma unroll
      for (int t = 0; t < 8; ++t) {
        int r = w * 8 + t;
        int rr = r & 63, sw = r & 15;
        tile[rr][lane ^ sw] = make_float2(dr[2 * t], di[2 * t]);
        tile[rr][(lane + 64) ^ sw] = make_float2(dr[2 * t + 1], di[2 * t + 1]);
      }
    }
    __syncthreads();
    {
      int sw = lane & 15;
#pragma unroll
      for (int ci = 0; ci < NC; ++ci) {
        int c = colbase + w * NC + ci;
        float2 v = tile[lane][c ^ sw];
        if (ch == 0) { er[ci] = v.x; ei[ci] = v.y; }
        else { fr[ci] = v.x; fi2[ci] = v.y; }
      }
    }
    __syncthreads();
  }
}

// ---------- 2-row path (k_fields) ----------
// g = lane>>5 row select, q = lane&31. Lane holds 4 pts c[m] at q+32m.
// R17: radix-4 merged in-register stage (spans 64+32), 3 shfl stages
// h=16,8,4, then trivial h=2, h=1. Slot 32m+q -> X[brev7(32m+q)].
// t2r/t2i[0..2]: h=16,8,4. hw: [0]=W128^q [2]=W64^q [4]=W128^3q (re,im pairs).
__device__ __forceinline__ void make_tw2(int q, float* t2r, float* t2i, float* hw) {
#pragma unroll
  for (int s = 0; s < 3; ++s) {
    int h = 16 >> s;
    float ang = -PI_F * (float)(q & (h - 1)) / (float)h;
    float sv, cv;
    __sincosf(ang, &sv, &cv);
    t2r[s] = cv; t2i[s] = sv;
  }
  float sv, cv;
  __sincosf(-PI_F * (float)q / 64.0f, &sv, &cv);        hw[0] = cv; hw[1] = sv;
  __sincosf(-PI_F * (float)q / 32.0f, &sv, &cv);        hw[2] = cv; hw[3] = sv;
  __sincosf(-3.0f * PI_F * (float)q / 64.0f, &sv, &cv); hw[4] = cv; hw[5] = sv;
}

template <int S>
__device__ __forceinline__ void fft128x2_dif(float (&cr)[4], float (&ci)[4],
    const float* t2r, const float* t2i, const float* hw, int q) {
  float T0r = hw[0], T0i = (S > 0) ? hw[1] : -hw[1];
  float T2r = hw[2], T2i = (S > 0) ? hw[3] : -hw[3];
  float T3r = hw[4], T3i = (S > 0) ? hw[5] : -hw[5];
  // radix-4 (exact merge of span-64 then span-32 radix-2 stages):
  // c0 = (t0+t2); c1 = (t0-t2)*W64^q; c2 = (t1 -si*i*t3)*W128^q;
  // c3 = (t1 +si*i*t3)*W128^3q   (si=+1 fwd, -1 inv)
  {
    float t0r = cr[0] + cr[2], t0i = ci[0] + ci[2];
    float t1r = cr[0] - cr[2], t1i = ci[0] - ci[2];
    float s2r = cr[1] + cr[3], s2i = ci[1] + ci[3];
    float t3r = cr[1] - cr[3], t3i = ci[1] - ci[3];
    cr[0] = t0r + s2r; ci[0] = t0i + s2i;
    float u1r = t0r - s2r, u1i = t0i - s2i;
    cr[1] = u1r * T2r - u1i * T2i; ci[1] = u1r * T2i + u1i * T2r;
    float v2r, v2i, v3r, v3i;
    if (S > 0) { v2r = t1r + t3i; v2i = t1i - t3r; v3r = t1r - t3i; v3i = t1i + t3r; }
    else       { v2r = t1r - t3i; v2i = t1i + t3r; v3r = t1r + t3i; v3i = t1i - t3r; }
    cr[2] = v2r * T0r - v2i * T0i; ci[2] = v2r * T0i + v2i * T0r;
    cr[3] = v3r * T3r - v3i * T3i; ci[3] = v3r * T3i + v3i * T3r;
  }
  // 3 shfl stages h=16,8,4
#pragma unroll
  for (int s = 0; s < 3; ++s) {
    int h = 16 >> s;
    float wr = t2r[s], wi = (S > 0) ? t2i[s] : -t2i[s];
    bool hi = (q & h) != 0;
#pragma unroll
    for (int m = 0; m < 4; ++m) {
      float pr = __shfl_xor(cr[m], h, 64);
      float pi2 = __shfl_xor(ci[m], h, 64);
      if (!hi) { cr[m] += pr; ci[m] += pi2; }
      else { float dr = pr - cr[m], di = pi2 - ci[m];
             cr[m] = dr * wr - di * wi; ci[m] = dr * wi + di * wr; }
    }
  }
  {  // h = 2: tw in {1, -i} fwd / {1, +i} inv
    bool hi = (q & 2) != 0, odd = (q & 1) != 0;
#pragma unroll
    for (int m = 0; m < 4; ++m) {
      float pr = __shfl_xor(cr[m], 2, 64);
      float pi2 = __shfl_xor(ci[m], 2, 64);
      if (!hi) { cr[m] += pr; ci[m] += pi2; }
      else {
        float dr = pr - cr[m], di = pi2 - ci[m];
        if (!odd) { cr[m] = dr; ci[m] = di; }
        else if (S > 0) { cr[m] = di; ci[m] = -dr; }
        else { cr[m] = -di; ci[m] = dr; }
      }
    }
  }
  {  // h = 1: tw = 1
    bool hi = (q & 1) != 0;
#pragma unroll
    for (int m = 0; m < 4; ++m) {
      float pr = __shfl_xor(cr[m], 1, 64);
      float pi2 = __shfl_xor(ci[m], 1, 64);
      if (!hi) { cr[m] += pr; ci[m] += pi2; }
      else { cr[m] = pr - cr[m]; ci[m] = pi2 - ci[m]; }
    }
  }
}

// blocks 0..15: (b,eighth): X[b] = fft2(x[b]) NATURAL (u,v) layout.
//   P1 [R16]: real-row pairing -- rows (2t,2t+1) as one complex FFT + unpack.
//   P2 [R17]: 1 call (16 cols per block).
// block 16: zero out[1344].
// blocks 17..148: G_j quarter: G_j(k) = 0.5*(F_j(k)^2 + F_j(-k)^2)
__global__ __launch_bounds__(1024, 2) void k_prep(const float* __restrict__ x,
    float2* __restrict__ X, float* __restrict__ out, const float* __restrict__ F,
    float* __restrict__ G) {
  __shared__ float2 tile[64][128];
  int tid = threadIdx.x;
  int bx = blockIdx.x;
  if (bx == 16) {
    if (tid < 1344) out[tid] = 0.f;
    return;
  }
  if (bx >= 17) {
    int q = bx - 17;
    int j = q >> 2, part = q & 3;
    const float* Fj = F + j * 16384;
    float* Gj = G + j * 16384;
#pragma unroll
    for (int it = 0; it < 4; ++it) {
      int k = part * 4096 + it * 1024 + tid;
      int u = k >> 7, v = k & 127;
      int un = (128 - u) & 127, vn = (128 - v) & 127;
      float f = Fj[k], fn = Fj[un * 128 + vn];
      Gj[k] = 0.5f * (f * f + fn * fn);
    }
    return;
  }
  int b = bx >> 3, eighth = bx & 7;
  int lane = tid & 63, w = tid >> 6;
  float twr[5], twi[5]; make_tw(lane, twr, twi);
  const float* xb = x + b * 16384;
  // lane-constant unpack slot indices:
  // a-slot freq v=u0 -> -v at slot brev7((128-u0)&127); b-slot v=u0+1.
  int u0 = __brev((unsigned)lane) >> 25;
  int spA = __brev((unsigned)((128 - u0) & 127)) >> 25;
  int spB = __brev((unsigned)(127 - u0)) >> 25;
  float dr[16], di[16];
  float er[1], ei[1], fr[1], fi2[1];
#pragma unroll
  for (int t = 0; t < 4; ++t) {  // P1: rows (2t, 2t+1) of this wave, paired
    int r0 = w * 8 + 2 * t;
    float ar = xb[r0 * 128 + lane],      ai2 = xb[(r0 + 1) * 128 + lane];
    float br = xb[r0 * 128 + lane + 64], bi  = xb[(r0 + 1) * 128 + lane + 64];
    fft128_dif<1>(ar, ai2, br, bi, twr, twi, lane);
    // unpack a-slot: fetch Z at slot spA (a-regs if <64 else b-regs)
    int la = spA & 63;
    float fAr = __shfl(ar, la, 64), fAi = __shfl(ai2, la, 64);
    float fBr = __shfl(br, la, 64), fBi = __shfl(bi, la, 64);
    float Pr = (spA < 64) ? fAr : fBr, Pi = (spA < 64) ? fAi : fBi;
    float X0r = 0.5f * (ar + Pr),  X0i = 0.5f * (ai2 - Pi);
    float X1r = 0.5f * (ai2 + Pi), X1i = 0.5f * (Pr - ar);
    // unpack b-slot
    int lb = spB & 63;
    float gAr = __shfl(ar, lb, 64), gAi = __shfl(ai2, lb, 64);
    float gBr = __shfl(br, lb, 64), gBi = __shfl(bi, lb, 64);
    float Qr = (spB < 64) ? gAr : gBr, Qi = (spB < 64) ? gAi : gBi;
    float Y0r = 0.5f * (br + Qr), Y0i = 0.5f * (bi - Qi);
    float Y1r = 0.5f * (bi + Qi), Y1i = 0.5f * (Qr - br);
    dr[2 * (2 * t)] = X0r;     di[2 * (2 * t)] = X0i;
    dr[2 * (2 * t) + 1] = Y0r; di[2 * (2 * t) + 1] = Y0i;
    dr[2 * (2 * t + 1)] = X1r;     di[2 * (2 * t + 1)] = X1i;
    dr[2 * (2 * t + 1) + 1] = Y1r; di[2 * (2 * t + 1) + 1] = Y1i;
  }
  transpose_r2c_n<1>(dr, di, er, ei, fr, fi2, tile, lane, w, eighth * 16);
  {  // P2 eighth: 1 call, col c = eighth*16 + w
    int c = eighth * 16 + w;
    float ar = er[0], ai2 = ei[0], br = fr[0], bi = fi2[0];
    fft128_dif<1>(ar, ai2, br, bi, twr, twi, lane);
    int vn = __brev((unsigned)c) >> 25;
    X[b * 16384 + u0 * 128 + vn] = make_float2(ar, ai2);
    X[b * 16384 + (u0 + 1) * 128 + vn] = make_float2(br, bi);
  }
}

// blocks 0..67:  d-pairs: (b x 17 pairs) x 2 halves.
//   pair p: j0=2p, j1=2p+1 (p<16); p==16 singleton j0=32.
//   Y = (G_j0 + i G_j1) * X; inv2_un(Y) = d_j0 + i d_j1.
// blocks 68..195: xa: (b*32+i) x 2 halves: xa = abs_eps(inv2_un(F_i X)/MN).
__global__ __launch_bounds__(1024, 1) void k_fields(const float2* __restrict__ X,
    const float* __restrict__ F, const float* __restrict__ G,
    float* __restrict__ dfld, float* __restrict__ xa) {
  __shared__ float2 tile[64][128];
  int tid = threadIdx.x, lane = tid & 63, w = tid >> 6;
  int g = lane >> 5, q = lane & 31;
  int bx = blockIdx.x;
  bool isd = (bx < 68);
  int b, half;
  bool has1 = false;
  const float* g0 = nullptr; const float* g1 = nullptr; const float* Fb = nullptr;
  float* o0; float* o1 = nullptr;
  if (isd) {
    int dp = bx >> 1; half = bx & 1;
    b = dp / 17; int p = dp - b * 17;
    int j0 = 2 * p; has1 = (p < 16);
    g0 = G + j0 * 16384;
    g1 = G + (j0 + 1) * 16384;
    o0 = dfld + (b * 33 + j0) * 16384;
    o1 = dfld + (b * 33 + j0 + 1) * 16384;
  } else {
    int qq = bx - 68; int qi = qq >> 1; half = qq & 1;
    b = qi >> 5; int f = qi & 31;
    Fb = F + f * 16384;
    o0 = xa + qi * 16384;
  }
  float t2r[3], t2i[3], hw[6];
  make_tw2(q, t2r, t2i, hw);
  const float2* Xb = X + b * 16384;

  // P1: 4 calls; call k does rows r0=w*8+2k (g=0) and r0+1 (g=1).
  float sr[4][4], si[4][4];
#pragma unroll
  for (int k = 0; k < 4; ++k) {
    int r = w * 8 + 2 * k + g;
    float cr[4], ci[4];
#pragma unroll
    for (int m = 0; m < 4; ++m) {
      int p = q + 32 * m;
      float2 xv = Xb[r * 128 + p];
      if (isd) {
        float ga = g0[r * 128 + p];
        float gb = has1 ? g1[r * 128 + p] : 0.f;
        cr[m] = xv.x * ga - xv.y * gb; ci[m] = xv.y * ga + xv.x * gb;
      } else {
        float f0 = Fb[r * 128 + p];
        cr[m] = xv.x * f0; ci[m] = xv.y * f0;
      }
    }
    fft128x2_dif<-1>(cr, ci, t2r, t2i, hw, q);
#pragma unroll
    for (int m = 0; m < 4; ++m) { sr[k][m] = cr[m]; si[k][m] = ci[m]; }
  }

  // Transpose: write slots (32m+q) of row r; read u-positions (32mm+q) of
  // cols c = colbase + w*4 + 2j + g. sw = row&15 both sides.
  float pr[2][4], pi2a[2][4];
  int colbase = half * 64;
#pragma unroll
  for (int ch = 0; ch < 2; ++ch) {
    if ((w >> 3) == ch) {
#pragma unroll
      for (int k = 0; k < 4; ++k) {
        int r = w * 8 + 2 * k + g;
        int rr = r & 63, sw = r & 15;
#pragma unroll
        for (int m = 0; m < 4; ++m)
          tile[rr][(32 * m + q) ^ sw] = make_float2(sr[k][m], si[k][m]);
      }
    }
    __syncthreads();
    {
      int sw = q & 15;
#pragma unroll
      for (int j = 0; j < 2; ++j) {
        int c = colbase + w * 4 + 2 * j + g;
#pragma unroll
        for (int mm = 0; mm < 2; ++mm) {
          float2 v = tile[32 * mm + q][c ^ sw];
          pr[j][2 * ch + mm] = v.x; pi2a[j][2 * ch + mm] = v.y;
        }
      }
    }
    __syncthreads();
  }

  // P2: 2 calls; call j does cols c0=colbase+w*4+2j (g=0) and c0+1 (g=1).
  const float sc = 1.0f / 16384.0f;
#pragma unroll
  for (int j = 0; j < 2; ++j) {
    fft128x2_dif<-1>(pr[j], pi2a[j], t2r, t2i, hw, q);
    int c = colbase + w * 4 + 2 * j + g;
#pragma unroll
    for (int m = 0; m < 4; ++m) {
      int su = 32 * m + q;
      if (isd) {
        o0[c * 128 + su] = pr[j][m];
        if (has1) o1[c * 128 + su] = pi2a[j][m];
      } else {
        float tr = pr[j][m] * sc, ti = pi2a[j][m] * sc;
        o0[c * 128 + su] = sqrtf(tr * tr + ti * ti + 1e-6f);
      }
    }
  }
}

// [R16] 1024 blocks = (b,i)[64] x slice[4] x jquarter[4]; 512 threads;
// acc[9]; j = 9*jq + t covers 0..35; j>=34 reads spill into xa workspace
// region (safe) and are discarded at emit (j<33 guard).
__global__ __launch_bounds__(512) void k_dot(const float* __restrict__ xa,
    const float* __restrict__ dfld, float* __restrict__ out) {
  int qb = blockIdx.x;
  int im = qb >> 4;                // 0..63  (b*32+i)
  int slice = (qb >> 2) & 3;       // 0..3
  int jq = qb & 3;                 // 0..3
  int b = im >> 5, i = im & 31;
  int j0 = jq * 9;                 // 0,9,18,27
  int t = threadIdx.x;             // 0..511
  const float4* xr = (const float4*)(xa + im * 16384 + slice * 4096);
  const float4* db = (const float4*)(dfld + (b * 33 + j0) * 16384 + slice * 4096);
  float acc[9];
#pragma unroll
  for (int j = 0; j < 9; ++j) acc[j] = 0.f;
#pragma unroll
  for (int it = 0; it < 2; ++it) {
    int k = it * 512 + t;          // float4 index, 1024 per slice
    float4 xv = xr[k];
#pragma unroll
    for (int j = 0; j < 9; ++j) {
      float4 dv = db[j * 4096 + k];
      acc[j] += xv.x * dv.x + xv.y * dv.y + xv.z * dv.z + xv.w * dv.w;
    }
  }
#pragma unroll
  for (int j = 0; j < 9; ++j) {
#pragma unroll
    for (int off = 32; off > 0; off >>= 1) acc[j] += __shfl_xor(acc[j], off, 64);
  }
  __shared__ float red[8][9];
  int w = t >> 6, lane = t & 63;
  if (lane == 0) {
#pragma unroll
    for (int j = 0; j < 9; ++j) red[w][j] = acc[j];
  }
  __syncthreads();
  if (t < 9) {
    int j = j0 + t;                // global j 0..35
    float s = 0.f;
#pragma unroll
    for (int w2 = 0; w2 < 8; ++w2) s += red[w2][t];
    int j1 = i >> 3, l1 = i & 7;
    const int pref[4] = {0, 264, 464, 600};
    int per = (4 - j1) * 8 + 1;
    int start = pref[j1] + l1 * per;
    int pos = -1;
    if (j == 32) pos = start + per - 1;
    else if (j < 32) {
      int j2 = j >> 3;
      if (j2 >= j1) pos = start + (j2 - j1) * 8 + (j & 7);
    }
    if (pos >= 0)
      atomicAdd(out + b * 672 + pos, s * (1.0f / 16384.0f) * (1.0f / 16384.0f));
  }
}

extern "C" void kernel_launch(void* const* d_in, const int* in_sizes, int n_in,
                              void* d_out, int out_size, void* d_ws, size_t ws_size,
                              hipStream_t stream) {
  (void)in_sizes; (void)n_in; (void)out_size; (void)ws_size;
  const float* x = (const float*)d_in[0];   // (2,1,128,128)
  const float* F = (const float*)d_in[1];   // (1,33,128,128)
  float* out = (float*)d_out;               // (2,672)
  char* ws = (char*)d_ws;
  // ws: X @0 (262144 B) | dfld @262144 (4325376 B) | xa @4587520 (4194304 B)
  //     | G @8781824 (2162688 B)
  float2* X = (float2*)(ws + 0);
  float* dfld = (float*)(ws + 262144);
  float* xa = (float*)(ws + 4587520);
  float* G = (float*)(ws + 8781824);

  hipLaunchKernelGGL(k_prep, dim3(149), dim3(1024), 0, stream, x, X, out, F, G);
  hipLaunchKernelGGL(k_fields, dim3(196), dim3(1024), 0, stream, X, F, G, dfld, xa);
  hipLaunchKernelGGL(k_dot, dim3(1024), dim3(512), 0, stream, xa, dfld, out);
}

// Round 8
// 95.043 us; speedup vs baseline: 1.0888x; 1.0088x over previous
//
#include <hip/hip_runtime.h>
#include <math.h>

// Third-order scattering via double-Parseval:
//   out[b,i,j] = (1/MN^2) * sum_n xa_{b,i}[n] * d_{b,j}[n]
// xa_i = abs_eps(inv2(F_i * X)/MN), d_j = Re(inv2_un(F_j^2 * X)), X = fft2(x).
// X in NATURAL frequency layout. Inverse FFTs are conjugate-DIF: natural freq
// input -> permuted spatial output. All k_fields outputs share one fixed
// permutation, so the spatial dot products are unaffected.
//
// Hard-won constraints / model:
//  - R7: cooperative single-kernel fusion regressed 2.8x. Do not fuse.
//  - R8/R9: inverse FFT MUST be conjugate-DIF (largest span FIRST,
//    forward-butterfly form, conjugated twiddles).
//  - R10: XCD-affine k_dot remap regressed; float4 alone (R12) is good.
//  - R11 FAILED: branchless fma-butterfly regressed. KEEP divergent if/else
//    butterflies (exception: stages with twiddle EXACTLY 1 or +-i).
//  - R12 WIN: k_dot float4. R13 WIN: Hermitian d-pairing + 2-block P2 split.
//  - R14 WIN: k_dot j-split + k_prep x4 split. 103.3us.
//  - R15 NEUTRAL: DS cuts don't move time. MODEL: FFT kernels are
//    VALU-ISSUE bound (DS hidden); wall ~ per-block VALU; d-blocks and
//    xa-blocks run on disjoint CUs, wall = max of the two.
//  - R16 WIN: real-row pairing + trivial h=1 + k_dot j-quarters. 96.7us.
//  - R17 WIN: trivial h=2, radix-4 in-register merge, k_prep x8. 95.9us.
//    Budget: fills ~85 (harness, fixed) + kernels ~8.5 + gaps ~2.5.
//  - R18 (this round): epilogue/operand VALU cuts on BOTH k_fields paths:
//    xa: abs_eps refold sc*sqrt(r^2+i^2+268.435456) w/ raw v_sqrt (4 ops vs
//    ~13); d: G packed as float2 pairs (4 clean loads vs 8 guarded, no
//    has1 selects in P1; singleton has .y=0). k_dot scale folded.
//
// 3 dispatches:
//  k_prep   : blocks 0-15: (b,eighth) X=fft2(x) w/ real-pair P1; 16: zero;
//             17-84: Gp pair quarters (float2).
//  k_fields : 196 blocks: 68 d-pair-half + 128 xa-half.
//  k_dot    : 1024 blocks = (b,i) x 4 k-slices x 4 j-quarters.

#define PI_F 3.14159265358979323846f

// ---------- 1-row path (k_prep) ----------
// twr/twi[0..3]: stages h=32,16,8,4; [4]: span-64 head W128^lane.
__device__ __forceinline__ void make_tw(int lane, float* twr, float* twi) {
#pragma unroll
  for (int s = 0; s < 4; ++s) {
    int h = 32 >> s;
    float ang = -PI_F * (float)(lane & (h - 1)) / (float)h;
    float sv, cv;
    __sincosf(ang, &sv, &cv);
    twr[s] = cv; twi[s] = sv;
  }
  float ang = -PI_F * (float)lane / 64.0f;
  float sv, cv;
  __sincosf(ang, &sv, &cv);
  twr[4] = cv; twi[4] = sv;
}

// DIF radix-2, 1 row/wave, 2 pts/lane. Natural in; slot s holds X[brev7(s)].
// h=2 (tw in {1,-i}) and h=1 (tw=1) stages hardcoded -- bit-equivalent.
template <int S>
__device__ __forceinline__ void fft128_dif(float& ar, float& ai, float& br, float& bi,
                                           const float* twr, const float* twi, int lane) {
  float s6r = twr[4], s6i = (S > 0) ? twi[4] : -twi[4];
  float ur = ar + br, ui = ai + bi;
  float vr = ar - br, vi = ai - bi;
  ar = ur; ai = ui;
  br = vr * s6r - vi * s6i;
  bi = vr * s6i + vi * s6r;
#pragma unroll
  for (int s = 0; s < 4; ++s) {  // h = 32,16,8,4
    int h = 32 >> s;
    float wr = twr[s], wi = (S > 0) ? twi[s] : -twi[s];
    bool hi = (lane & h) != 0;
    float pr, pi2;
    pr = __shfl_xor(ar, h, 64); pi2 = __shfl_xor(ai, h, 64);
    if (!hi) { ar += pr; ai += pi2; }
    else { float dr = pr - ar, di = pi2 - ai; ar = dr * wr - di * wi; ai = dr * wi + di * wr; }
    pr = __shfl_xor(br, h, 64); pi2 = __shfl_xor(bi, h, 64);
    if (!hi) { br += pr; bi += pi2; }
    else { float dr = pr - br, di = pi2 - bi; br = dr * wr - di * wi; bi = dr * wi + di * wr; }
  }
  {  // h = 2: tw in {1, -i} fwd / {1, +i} inv -> swap/negate
    bool hi = (lane & 2) != 0, odd = (lane & 1) != 0;
    float pr, pi2;
    pr = __shfl_xor(ar, 2, 64); pi2 = __shfl_xor(ai, 2, 64);
    if (!hi) { ar += pr; ai += pi2; }
    else {
      float dr = pr - ar, di = pi2 - ai;
      if (!odd) { ar = dr; ai = di; }
      else if (S > 0) { ar = di; ai = -dr; }
      else { ar = -di; ai = dr; }
    }
    pr = __shfl_xor(br, 2, 64); pi2 = __shfl_xor(bi, 2, 64);
    if (!hi) { br += pr; bi += pi2; }
    else {
      float dr = pr - br, di = pi2 - bi;
      if (!odd) { br = dr; bi = di; }
      else if (S > 0) { br = di; bi = -dr; }
      else { br = -di; bi = dr; }
    }
  }
  {  // h = 1: tw = 1
    bool hi = (lane & 1) != 0;
    float pr, pi2;
    pr = __shfl_xor(ar, 1, 64); pi2 = __shfl_xor(ai, 1, 64);
    if (!hi) { ar += pr; ai += pi2; } else { ar = pr - ar; ai = pi2 - ai; }
    pr = __shfl_xor(br, 1, 64); pi2 = __shfl_xor(bi, 1, 64);
    if (!hi) { br += pr; bi += pi2; } else { br = pr - br; bi = pi2 - bi; }
  }
}

template <int NC>
__device__ __forceinline__ void transpose_r2c_n(float (&dr)[16], float (&di)[16],
    float (&er)[NC], float (&ei)[NC], float (&fr)[NC], float (&fi2)[NC],
    float2 (*tile)[128], int lane, int w, int colbase) {
#pragma unroll
  for (int ch = 0; ch < 2; ++ch) {
    if ((w >> 3) == ch) {
#pragma unroll
      for (int t = 0; t < 8; ++t) {
        int r = w * 8 + t;
        int rr = r & 63, sw = r & 15;
        tile[rr][lane ^ sw] = make_float2(dr[2 * t], di[2 * t]);
        tile[rr][(lane + 64) ^ sw] = make_float2(dr[2 * t + 1], di[2 * t + 1]);
      }
    }
    __syncthreads();
    {
      int sw = lane & 15;
#pragma unroll
      for (int ci = 0; ci < NC; ++ci) {
        int c = colbase + w * NC + ci;
        float2 v = tile[lane][c ^ sw];
        if (ch == 0) { er[ci] = v.x; ei[ci] = v.y; }
        else { fr[ci] = v.x; fi2[ci] = v.y; }
      }
    }
    __syncthreads();
  }
}

// ---------- 2-row path (k_fields) ----------
// g = lane>>5 row select, q = lane&31. Lane holds 4 pts c[m] at q+32m.
// Radix-4 merged in-register stage (spans 64+32), 3 shfl stages h=16,8,4,
// then trivial h=2, h=1. Slot 32m+q -> X[brev7(32m+q)].
// t2r/t2i[0..2]: h=16,8,4. hw: [0]=W128^q [2]=W64^q [4]=W128^3q (re,im pairs).
__device__ __forceinline__ void make_tw2(int q, float* t2r, float* t2i, float* hw) {
#pragma unroll
  for (int s = 0; s < 3; ++s) {
    int h = 16 >> s;
    float ang = -PI_F * (float)(q & (h - 1)) / (float)h;
    float sv, cv;
    __sincosf(ang, &sv, &cv);
    t2r[s] = cv; t2i[s] = sv;
  }
  float sv, cv;
  __sincosf(-PI_F * (float)q / 64.0f, &sv, &cv);        hw[0] = cv; hw[1] = sv;
  __sincosf(-PI_F * (float)q / 32.0f, &sv, &cv);        hw[2] = cv; hw[3] = sv;
  __sincosf(-3.0f * PI_F * (float)q / 64.0f, &sv, &cv); hw[4] = cv; hw[5] = sv;
}

template <int S>
__device__ __forceinline__ void fft128x2_dif(float (&cr)[4], float (&ci)[4],
    const float* t2r, const float* t2i, const float* hw, int q) {
  float T0r = hw[0], T0i = (S > 0) ? hw[1] : -hw[1];
  float T2r = hw[2], T2i = (S > 0) ? hw[3] : -hw[3];
  float T3r = hw[4], T3i = (S > 0) ? hw[5] : -hw[5];
  // radix-4 (exact merge of span-64 then span-32 radix-2 stages)
  {
    float t0r = cr[0] + cr[2], t0i = ci[0] + ci[2];
    float t1r = cr[0] - cr[2], t1i = ci[0] - ci[2];
    float s2r = cr[1] + cr[3], s2i = ci[1] + ci[3];
    float t3r = cr[1] - cr[3], t3i = ci[1] - ci[3];
    cr[0] = t0r + s2r; ci[0] = t0i + s2i;
    float u1r = t0r - s2r, u1i = t0i - s2i;
    cr[1] = u1r * T2r - u1i * T2i; ci[1] = u1r * T2i + u1i * T2r;
    float v2r, v2i, v3r, v3i;
    if (S > 0) { v2r = t1r + t3i; v2i = t1i - t3r; v3r = t1r - t3i; v3i = t1i + t3r; }
    else       { v2r = t1r - t3i; v2i = t1i + t3r; v3r = t1r + t3i; v3i = t1i - t3r; }
    cr[2] = v2r * T0r - v2i * T0i; ci[2] = v2r * T0i + v2i * T0r;
    cr[3] = v3r * T3r - v3i * T3i; ci[3] = v3r * T3i + v3i * T3r;
  }
  // 3 shfl stages h=16,8,4
#pragma unroll
  for (int s = 0; s < 3; ++s) {
    int h = 16 >> s;
    float wr = t2r[s], wi = (S > 0) ? t2i[s] : -t2i[s];
    bool hi = (q & h) != 0;
#pragma unroll
    for (int m = 0; m < 4; ++m) {
      float pr = __shfl_xor(cr[m], h, 64);
      float pi2 = __shfl_xor(ci[m], h, 64);
      if (!hi) { cr[m] += pr; ci[m] += pi2; }
      else { float dr = pr - cr[m], di = pi2 - ci[m];
             cr[m] = dr * wr - di * wi; ci[m] = dr * wi + di * wr; }
    }
  }
  {  // h = 2: tw in {1, -i} fwd / {1, +i} inv
    bool hi = (q & 2) != 0, odd = (q & 1) != 0;
#pragma unroll
    for (int m = 0; m < 4; ++m) {
      float pr = __shfl_xor(cr[m], 2, 64);
      float pi2 = __shfl_xor(ci[m], 2, 64);
      if (!hi) { cr[m] += pr; ci[m] += pi2; }
      else {
        float dr = pr - cr[m], di = pi2 - ci[m];
        if (!odd) { cr[m] = dr; ci[m] = di; }
        else if (S > 0) { cr[m] = di; ci[m] = -dr; }
        else { cr[m] = -di; ci[m] = dr; }
      }
    }
  }
  {  // h = 1: tw = 1
    bool hi = (q & 1) != 0;
#pragma unroll
    for (int m = 0; m < 4; ++m) {
      float pr = __shfl_xor(cr[m], 1, 64);
      float pi2 = __shfl_xor(ci[m], 1, 64);
      if (!hi) { cr[m] += pr; ci[m] += pi2; }
      else { cr[m] = pr - cr[m]; ci[m] = pi2 - ci[m]; }
    }
  }
}

// blocks 0..15: (b,eighth): X[b] = fft2(x[b]) NATURAL (u,v) layout.
//   P1: real-row pairing; P2: 1 call (16 cols per block).
// block 16: zero out[1344].
// blocks 17..84: Gp pair quarters [R18]:
//   Gp[p][k] = (G_{2p}(k), G_{2p+1}(k)) float2; p==16 -> (G_32(k), 0).
//   G_j(k) = 0.5*(F_j(k)^2 + F_j(-k)^2).
__global__ __launch_bounds__(1024, 2) void k_prep(const float* __restrict__ x,
    float2* __restrict__ X, float* __restrict__ out, const float* __restrict__ F,
    float2* __restrict__ Gp) {
  __shared__ float2 tile[64][128];
  int tid = threadIdx.x;
  int bx = blockIdx.x;
  if (bx == 16) {
    if (tid < 1344) out[tid] = 0.f;
    return;
  }
  if (bx >= 17) {
    int qq = bx - 17;              // 0..67
    int p = qq >> 2, part = qq & 3;
    bool hp = (p < 16);
    const float* F0 = F + (2 * p) * 16384;
    const float* F1 = F + (2 * p + 1) * 16384;
    float2* Gj = Gp + p * 16384;
#pragma unroll
    for (int it = 0; it < 4; ++it) {
      int k = part * 4096 + it * 1024 + tid;
      int u = k >> 7, v = k & 127;
      int kneg = (((128 - u) & 127) << 7) | ((128 - v) & 127);
      float f = F0[k], fn = F0[kneg];
      float g0v = 0.5f * (f * f + fn * fn);
      float g1v = 0.f;
      if (hp) {
        float e = F1[k], en = F1[kneg];
        g1v = 0.5f * (e * e + en * en);
      }
      Gj[k] = make_float2(g0v, g1v);
    }
    return;
  }
  int b = bx >> 3, eighth = bx & 7;
  int lane = tid & 63, w = tid >> 6;
  float twr[5], twi[5]; make_tw(lane, twr, twi);
  const float* xb = x + b * 16384;
  // lane-constant unpack slot indices:
  // a-slot freq v=u0 -> -v at slot brev7((128-u0)&127); b-slot v=u0+1.
  int u0 = __brev((unsigned)lane) >> 25;
  int spA = __brev((unsigned)((128 - u0) & 127)) >> 25;
  int spB = __brev((unsigned)(127 - u0)) >> 25;
  float dr[16], di[16];
  float er[1], ei[1], fr[1], fi2[1];
#pragma unroll
  for (int t = 0; t < 4; ++t) {  // P1: rows (2t, 2t+1) of this wave, paired
    int r0 = w * 8 + 2 * t;
    float ar = xb[r0 * 128 + lane],      ai2 = xb[(r0 + 1) * 128 + lane];
    float br = xb[r0 * 128 + lane + 64], bi  = xb[(r0 + 1) * 128 + lane + 64];
    fft128_dif<1>(ar, ai2, br, bi, twr, twi, lane);
    // unpack a-slot: fetch Z at slot spA (a-regs if <64 else b-regs)
    int la = spA & 63;
    float fAr = __shfl(ar, la, 64), fAi = __shfl(ai2, la, 64);
    float fBr = __shfl(br, la, 64), fBi = __shfl(bi, la, 64);
    float Pr = (spA < 64) ? fAr : fBr, Pi = (spA < 64) ? fAi : fBi;
    float X0r = 0.5f * (ar + Pr),  X0i = 0.5f * (ai2 - Pi);
    float X1r = 0.5f * (ai2 + Pi), X1i = 0.5f * (Pr - ar);
    // unpack b-slot
    int lb = spB & 63;
    float gAr = __shfl(ar, lb, 64), gAi = __shfl(ai2, lb, 64);
    float gBr = __shfl(br, lb, 64), gBi = __shfl(bi, lb, 64);
    float Qr = (spB < 64) ? gAr : gBr, Qi = (spB < 64) ? gAi : gBi;
    float Y0r = 0.5f * (br + Qr), Y0i = 0.5f * (bi - Qi);
    float Y1r = 0.5f * (bi + Qi), Y1i = 0.5f * (Qr - br);
    dr[2 * (2 * t)] = X0r;     di[2 * (2 * t)] = X0i;
    dr[2 * (2 * t) + 1] = Y0r; di[2 * (2 * t) + 1] = Y0i;
    dr[2 * (2 * t + 1)] = X1r;     di[2 * (2 * t + 1)] = X1i;
    dr[2 * (2 * t + 1) + 1] = Y1r; di[2 * (2 * t + 1) + 1] = Y1i;
  }
  transpose_r2c_n<1>(dr, di, er, ei, fr, fi2, tile, lane, w, eighth * 16);
  {  // P2 eighth: 1 call, col c = eighth*16 + w
    int c = eighth * 16 + w;
    float ar = er[0], ai2 = ei[0], br = fr[0], bi = fi2[0];
    fft128_dif<1>(ar, ai2, br, bi, twr, twi, lane);
    int vn = __brev((unsigned)c) >> 25;
    X[b * 16384 + u0 * 128 + vn] = make_float2(ar, ai2);
    X[b * 16384 + (u0 + 1) * 128 + vn] = make_float2(br, bi);
  }
}

// blocks 0..67:  d-pairs: (b x 17 pairs) x 2 halves.
//   Y = (Gp.x + i Gp.y) * X; inv2_un(Y) = d_j0 + i d_j1 (singleton: .y=0).
// blocks 68..195: xa: (b*32+i) x 2 halves: xa = abs_eps(inv2_un(F_i X)/MN).
__global__ __launch_bounds__(1024, 1) void k_fields(const float2* __restrict__ X,
    const float* __restrict__ F, const float2* __restrict__ Gp,
    float* __restrict__ dfld, float* __restrict__ xa) {
  __shared__ float2 tile[64][128];
  int tid = threadIdx.x, lane = tid & 63, w = tid >> 6;
  int g = lane >> 5, q = lane & 31;
  int bx = blockIdx.x;
  bool isd = (bx < 68);
  int b, half;
  bool has1 = false;
  const float2* gpp = nullptr; const float* Fb = nullptr;
  float* o0; float* o1 = nullptr;
  if (isd) {
    int dp = bx >> 1; half = bx & 1;
    b = dp / 17; int p = dp - b * 17;
    int j0 = 2 * p; has1 = (p < 16);
    gpp = Gp + p * 16384;
    o0 = dfld + (b * 33 + j0) * 16384;
    o1 = dfld + (b * 33 + j0 + 1) * 16384;
  } else {
    int qq = bx - 68; int qi = qq >> 1; half = qq & 1;
    b = qi >> 5; int f = qi & 31;
    Fb = F + f * 16384;
    o0 = xa + qi * 16384;
  }
  float t2r[3], t2i[3], hw[6];
  make_tw2(q, t2r, t2i, hw);
  const float2* Xb = X + b * 16384;

  // P1: 4 calls; call k does rows r0=w*8+2k (g=0) and r0+1 (g=1).
  float sr[4][4], si[4][4];
#pragma unroll
  for (int k = 0; k < 4; ++k) {
    int r = w * 8 + 2 * k + g;
    float cr[4], ci[4];
#pragma unroll
    for (int m = 0; m < 4; ++m) {
      int p = q + 32 * m;
      float2 xv = Xb[r * 128 + p];
      if (isd) {
        float2 gv = gpp[r * 128 + p];
        cr[m] = xv.x * gv.x - xv.y * gv.y; ci[m] = xv.y * gv.x + xv.x * gv.y;
      } else {
        float f0 = Fb[r * 128 + p];
        cr[m] = xv.x * f0; ci[m] = xv.y * f0;
      }
    }
    fft128x2_dif<-1>(cr, ci, t2r, t2i, hw, q);
#pragma unroll
    for (int m = 0; m < 4; ++m) { sr[k][m] = cr[m]; si[k][m] = ci[m]; }
  }

  // Transpose: write slots (32m+q) of row r; read u-positions (32mm+q) of
  // cols c = colbase + w*4 + 2j + g. sw = row&15 both sides.
  float pr[2][4], pi2a[2][4];
  int colbase = half * 64;
#pragma unroll
  for (int ch = 0; ch < 2; ++ch) {
    if ((w >> 3) == ch) {
#pragma unroll
      for (int k = 0; k < 4; ++k) {
        int r = w * 8 + 2 * k + g;
        int rr = r & 63, sw = r & 15;
#pragma unroll
        for (int m = 0; m < 4; ++m)
          tile[rr][(32 * m + q) ^ sw] = make_float2(sr[k][m], si[k][m]);
      }
    }
    __syncthreads();
    {
      int sw = q & 15;
#pragma unroll
      for (int j = 0; j < 2; ++j) {
        int c = colbase + w * 4 + 2 * j + g;
#pragma unroll
        for (int mm = 0; mm < 2; ++mm) {
          float2 v = tile[32 * mm + q][c ^ sw];
          pr[j][2 * ch + mm] = v.x; pi2a[j][2 * ch + mm] = v.y;
        }
      }
    }
    __syncthreads();
  }

  // P2: 2 calls; call j does cols c0=colbase+w*4+2j (g=0) and c0+1 (g=1).
  // xa epilogue [R18]: sc*sqrt(r^2+i^2 + 1e-6/sc^2), raw v_sqrt.
  const float sc = 1.0f / 16384.0f;
  const float epsS = 268.435456f;  // 1e-6 / sc^2
#pragma unroll
  for (int j = 0; j < 2; ++j) {
    fft128x2_dif<-1>(pr[j], pi2a[j], t2r, t2i, hw, q);
    int c = colbase + w * 4 + 2 * j + g;
#pragma unroll
    for (int m = 0; m < 4; ++m) {
      int su = 32 * m + q;
      if (isd) {
        o0[c * 128 + su] = pr[j][m];
        if (has1) o1[c * 128 + su] = pi2a[j][m];
      } else {
        float tr = pr[j][m], ti = pi2a[j][m];
        float mag = __builtin_amdgcn_sqrtf(fmaf(tr, tr, fmaf(ti, ti, epsS)));
        o0[c * 128 + su] = mag * sc;
      }
    }
  }
}

// 1024 blocks = (b,i)[64] x slice[4] x jquarter[4]; 512 threads; acc[9];
// j = 9*jq + t covers 0..35; j>=34 reads spill into xa workspace region
// (safe) and are discarded at emit (j<33 guard).
__global__ __launch_bounds__(512) void k_dot(const float* __restrict__ xa,
    const float* __restrict__ dfld, float* __restrict__ out) {
  int qb = blockIdx.x;
  int im = qb >> 4;                // 0..63  (b*32+i)
  int slice = (qb >> 2) & 3;       // 0..3
  int jq = qb & 3;                 // 0..3
  int b = im >> 5, i = im & 31;
  int j0 = jq * 9;                 // 0,9,18,27
  int t = threadIdx.x;             // 0..511
  const float4* xr = (const float4*)(xa + im * 16384 + slice * 4096);
  const float4* db = (const float4*)(dfld + (b * 33 + j0) * 16384 + slice * 4096);
  float acc[9];
#pragma unroll
  for (int j = 0; j < 9; ++j) acc[j] = 0.f;
#pragma unroll
  for (int it = 0; it < 2; ++it) {
    int k = it * 512 + t;          // float4 index, 1024 per slice
    float4 xv = xr[k];
#pragma unroll
    for (int j = 0; j < 9; ++j) {
      float4 dv = db[j * 4096 + k];
      acc[j] += xv.x * dv.x + xv.y * dv.y + xv.z * dv.z + xv.w * dv.w;
    }
  }
#pragma unroll
  for (int j = 0; j < 9; ++j) {
#pragma unroll
    for (int off = 32; off > 0; off >>= 1) acc[j] += __shfl_xor(acc[j], off, 64);
  }
  __shared__ float red[8][9];
  int w = t >> 6, lane = t & 63;
  if (lane == 0) {
#pragma unroll
    for (int j = 0; j < 9; ++j) red[w][j] = acc[j];
  }
  __syncthreads();
  if (t < 9) {
    int j = j0 + t;                // global j 0..35
    float s = 0.f;
#pragma unroll
    for (int w2 = 0; w2 < 8; ++w2) s += red[w2][t];
    int j1 = i >> 3, l1 = i & 7;
    const int pref[4] = {0, 264, 464, 600};
    int per = (4 - j1) * 8 + 1;
    int start = pref[j1] + l1 * per;
    int pos = -1;
    if (j == 32) pos = start + per - 1;
    else if (j < 32) {
      int j2 = j >> 3;
      if (j2 >= j1) pos = start + (j2 - j1) * 8 + (j & 7);
    }
    if (pos >= 0)
      atomicAdd(out + b * 672 + pos, s * 3.725290298461914e-09f);  // 1/16384^2
  }
}

extern "C" void kernel_launch(void* const* d_in, const int* in_sizes, int n_in,
                              void* d_out, int out_size, void* d_ws, size_t ws_size,
                              hipStream_t stream) {
  (void)in_sizes; (void)n_in; (void)out_size; (void)ws_size;
  const float* x = (const float*)d_in[0];   // (2,1,128,128)
  const float* F = (const float*)d_in[1];   // (1,33,128,128)
  float* out = (float*)d_out;               // (2,672)
  char* ws = (char*)d_ws;
  // ws: X @0 (262144 B) | dfld @262144 (4325376 B) | xa @4587520 (4194304 B)
  //     | Gp @8781824 (2228224 B, float2[17*16384])
  float2* X = (float2*)(ws + 0);
  float* dfld = (float*)(ws + 262144);
  float* xa = (float*)(ws + 4587520);
  float2* Gp = (float2*)(ws + 8781824);

  hipLaunchKernelGGL(k_prep, dim3(85), dim3(1024), 0, stream, x, X, out, F, Gp);
  hipLaunchKernelGGL(k_fields, dim3(196), dim3(1024), 0, stream, X, F, Gp, dfld, xa);
  hipLaunchKernelGGL(k_dot, dim3(1024), dim3(512), 0, stream, xa, dfld, out);
}